// Round 3
// baseline (312.937 us; speedup 1.0000x reference)
//
#include <hip/hip_runtime.h>
#include <math.h>

typedef _Float16 v8h __attribute__((ext_vector_type(8)));
typedef float v4f __attribute__((ext_vector_type(4)));

#define UNITS    50
#define K3       150
#define FDIM     64
#define TSTEPS   128
#define BATCH    4096
#define NB       16     // batch rows per wave tile (MFMA N)

#if __has_builtin(__builtin_amdgcn_exp2f)
__device__ __forceinline__ float fast_exp2(float x) { return __builtin_amdgcn_exp2f(x); }
#else
__device__ __forceinline__ float fast_exp2(float x) { return exp2f(x); }
#endif
#if __has_builtin(__builtin_amdgcn_rcpf)
__device__ __forceinline__ float fast_rcp(float x) { return __builtin_amdgcn_rcpf(x); }
#else
__device__ __forceinline__ float fast_rcp(float x) { return 1.0f / x; }
#endif

// Single-wave, barrier-free GRU tile. Operands SWAPPED vs the 4-wave design:
//   M = gate-units (weights are the MFMA A operand), N = batch rows.
// C layout (col=lane&15=batch n, row=(lane>>4)*4+reg = unit within M-tile)
// means lane (q,n) holds gate values for units {mt*16+q*4+r}, batch n.
// The h-part K-ordering of U is PERMUTED (sigma) so that k-slot (kt,q,j)
// = unit ((kt-2)*2+(j>>2))*16 + q*4 + (j&3): the B-fragment a lane needs
// next step is exactly the 16 h values it already holds -> the entire
// recurrence is register-local. No LDS, no barriers, no cross-lane ops in
// the loop. 48 MFMAs/step on one SIMD is the new floor (~768 cy/step).
//
// Bias folding:
//  - z,r,hh biases ride a spare k-slot (kt=3,q=0,j=6; padding unit 50) whose
//    B value is forced to 1.0 on q==0 lanes. ez = exp2(Cz*CE) directly.
//  - h-gate x-bias (b[0] col 100+) rides the C-init of the Chx chain (f32 exact).
// Dead M rows (units 50..63) have all-zero A rows -> their h stays 0 (finite).
__global__ __launch_bounds__(64, 1)
void gru_1w(const float* __restrict__ x, const float* __restrict__ W,
            const float* __restrict__ U, const float* __restrict__ bv,
            const float* __restrict__ Wd, const float* __restrict__ bd,
            float* __restrict__ out) {
    const int lane = threadIdx.x & 63;
    const int n    = lane & 15;     // batch col (B/C) AND unit row m15 (A)
    const int q    = lane >> 4;     // k-group for A/B; row-quad for C
    const int b0   = blockIdx.x * NB;

    // ---- A fragments: weights, M=units, K = [64 x-feats | sigma-packed h] ----
    v8h Az[4][4], Ar[4][4], Ah[4][4];
    #pragma unroll
    for (int mt = 0; mt < 4; ++mt) {
        const int m = mt * 16 + n;          // unit (M row)
        const bool mreal = (m < UNITS);
        #pragma unroll
        for (int kt = 0; kt < 4; ++kt) {
            v8h fz, fr, fh;
            #pragma unroll
            for (int j = 0; j < 8; ++j) {
                float vz = 0.f, vr = 0.f, vh = 0.f;
                if (mreal) {
                    if (kt < 2) {
                        const int feat = kt * 32 + q * 8 + j;
                        vz = W[feat * K3 + m];
                        vr = W[feat * K3 + 50 + m];
                        vh = W[feat * K3 + 100 + m];
                    } else if (kt == 3 && q == 0 && j == 6) {
                        vz = bv[m]      + bv[150 + m];   // b0z + b1z
                        vr = bv[50 + m] + bv[200 + m];   // b0r + b1r
                        vh = bv[250 + m];                // b1h (inside r*hh)
                    } else {
                        const int u = ((kt - 2) * 2 + (j >> 2)) * 16 + q * 4 + (j & 3);
                        if (u < UNITS) {
                            vz = U[u * K3 + m];
                            vr = U[u * K3 + 50 + m];
                            vh = U[u * K3 + 100 + m];
                        }
                    }
                }
                fz[j] = (_Float16)vz; fr[j] = (_Float16)vr; fh[j] = (_Float16)vh;
            }
            Az[mt][kt] = fz; Ar[mt][kt] = fr; Ah[mt][kt] = fh;
        }
    }

    // ---- C-init constants for the h-gate x-part: b[0] col 100+u (f32 exact) ----
    v4f bx4[4];
    #pragma unroll
    for (int mt = 0; mt < 4; ++mt)
        #pragma unroll
        for (int r = 0; r < 4; ++r) {
            const int u = mt * 16 + q * 4 + r;
            bx4[mt][r] = (u < UNITS) ? bv[100 + u] : 0.f;
        }

    const float CE = -1.44269504f;          // sigmoid(a) = 1/(1 + 2^(CE*a))

    // h state f32: h32[mt][r] = h[unit mt*16+q*4+r][batch n]
    v4f h32[4];
    #pragma unroll
    for (int mt = 0; mt < 4; ++mt) h32[mt] = v4f{0.f, 0.f, 0.f, 0.f};

    // ---- x prefetch: lane covers batch row b0+n, feats q*8..+7 and 32+q*8..+7 ----
    const float* xb = x + ((size_t)(b0 + n) * TSTEPS) * FDIM + q * 8;
    v4f pxA[4], pxB[4];
    pxA[0] = *(const v4f*)(xb + 0);  pxA[1] = *(const v4f*)(xb + 4);
    pxA[2] = *(const v4f*)(xb + 32); pxA[3] = *(const v4f*)(xb + 36);
    {
        const float* x1 = xb + (size_t)FDIM;
        pxB[0] = *(const v4f*)(x1 + 0);  pxB[1] = *(const v4f*)(x1 + 4);
        pxB[2] = *(const v4f*)(x1 + 32); pxB[3] = *(const v4f*)(x1 + 36);
    }

    auto step = [&](int t, v4f (&px)[4]) {
        // B0,B1: x K-tiles (feats 0..31 | 32..63)
        v8h B0, B1;
        #pragma unroll
        for (int j = 0; j < 4; ++j) {
            B0[j]     = (_Float16)px[0][j];
            B0[j + 4] = (_Float16)px[1][j];
            B1[j]     = (_Float16)px[2][j];
            B1[j + 4] = (_Float16)px[3][j];
        }
        const v4f z4 = {0.f, 0.f, 0.f, 0.f};
        v4f Cz[4], Cr[4], Chx[4], Chh[4];
        // x-part MFMAs (kt0 then kt1; dependent pairs 12 apart -> pipelined)
        #pragma unroll
        for (int mt = 0; mt < 4; ++mt) {
            Cz[mt]  = __builtin_amdgcn_mfma_f32_16x16x32_f16(Az[mt][0], B0, z4,       0, 0, 0);
            Cr[mt]  = __builtin_amdgcn_mfma_f32_16x16x32_f16(Ar[mt][0], B0, z4,       0, 0, 0);
            Chx[mt] = __builtin_amdgcn_mfma_f32_16x16x32_f16(Ah[mt][0], B0, bx4[mt],  0, 0, 0);
        }
        #pragma unroll
        for (int mt = 0; mt < 4; ++mt) {
            Cz[mt]  = __builtin_amdgcn_mfma_f32_16x16x32_f16(Az[mt][1], B1, Cz[mt],  0, 0, 0);
            Cr[mt]  = __builtin_amdgcn_mfma_f32_16x16x32_f16(Ar[mt][1], B1, Cr[mt],  0, 0, 0);
            Chx[mt] = __builtin_amdgcn_mfma_f32_16x16x32_f16(Ah[mt][1], B1, Chx[mt], 0, 0, 0);
        }
        // prefetch x(t+2) into this buffer (vmcnt waited only next iteration)
        if (t + 2 < TSTEPS) {
            const float* xp = xb + (size_t)(t + 2) * FDIM;
            px[0] = *(const v4f*)(xp + 0);
            px[1] = *(const v4f*)(xp + 4);
            px[2] = *(const v4f*)(xp + 32);
            px[3] = *(const v4f*)(xp + 36);
        }
        // B2,B3: h K-tiles — the lane's OWN h values (sigma ordering), in-lane cvt
        v8h B2, B3;
        #pragma unroll
        for (int j = 0; j < 8; ++j) B2[j] = (_Float16)h32[j >> 2][j & 3];
        B3[0] = (_Float16)h32[2][0]; B3[1] = (_Float16)h32[2][1];
        B3[2] = (_Float16)h32[2][2]; B3[3] = (_Float16)h32[2][3];
        B3[4] = (_Float16)h32[3][0]; B3[5] = (_Float16)h32[3][1];
        B3[6] = (q == 0) ? (_Float16)1.f : (_Float16)0.f;   // bias row (unit-50 slot)
        B3[7] = (_Float16)0.f;                              // dead (unit-51 slot)
        // h-part MFMAs
        #pragma unroll
        for (int mt = 0; mt < 4; ++mt) {
            Cz[mt]  = __builtin_amdgcn_mfma_f32_16x16x32_f16(Az[mt][2], B2, Cz[mt],  0, 0, 0);
            Cr[mt]  = __builtin_amdgcn_mfma_f32_16x16x32_f16(Ar[mt][2], B2, Cr[mt],  0, 0, 0);
            Chh[mt] = __builtin_amdgcn_mfma_f32_16x16x32_f16(Ah[mt][2], B2, z4,      0, 0, 0);
        }
        #pragma unroll
        for (int mt = 0; mt < 4; ++mt) {
            Cz[mt]  = __builtin_amdgcn_mfma_f32_16x16x32_f16(Az[mt][3], B3, Cz[mt],  0, 0, 0);
            Cr[mt]  = __builtin_amdgcn_mfma_f32_16x16x32_f16(Ar[mt][3], B3, Cr[mt],  0, 0, 0);
            Chh[mt] = __builtin_amdgcn_mfma_f32_16x16x32_f16(Ah[mt][3], B3, Chh[mt], 0, 0, 0);
        }
        // gate math, register-local; skip all-dead regs (units 50..63 at mt3 r2,r3)
        #pragma unroll
        for (int mt = 0; mt < 4; ++mt) {
            #pragma unroll
            for (int r = 0; r < 4; ++r) {
                if (mt == 3 && r >= 2) continue;
                const float ez = fast_exp2(Cz[mt][r] * CE);   // biases already in Cz
                const float er = fast_exp2(Cr[mt][r] * CE);
                const float pz = 1.f + ez;
                const float pr = 1.f + er;
                const float d  = fast_rcp(pz * pr);
                const float zg = d * pr;                      // sigmoid(z-pre)
                const float rg = d * pz;                      // sigmoid(r-pre)
                const float hc = fmaxf(fmaf(rg, Chh[mt][r], Chx[mt][r]), 0.f);
                h32[mt][r] = fmaf(zg, h32[mt][r] - hc, hc);   // z*h + (1-z)*hc
            }
        }
    };

    #pragma unroll 1
    for (int t = 0; t < TSTEPS; t += 2) {
        step(t,     pxA);
        step(t + 1, pxB);
    }

    // ---- epilogue: out[b] = h_T @ Wd + bd (exact f32 h; reduce over q-groups) ----
    float acc = 0.f;
    #pragma unroll
    for (int mt = 0; mt < 3; ++mt)          // units 0..47: always real
        #pragma unroll
        for (int r = 0; r < 4; ++r)
            acc = fmaf(h32[mt][r], Wd[mt * 16 + q * 4 + r], acc);
    if (q == 0) {                           // units 48,49
        acc = fmaf(h32[3][0], Wd[48], acc);
        acc = fmaf(h32[3][1], Wd[49], acc);
    }
    acc += __shfl_xor(acc, 16, 64);
    acc += __shfl_xor(acc, 32, 64);
    if (q == 0) out[b0 + n] = acc + bd[0];
}

extern "C" void kernel_launch(void* const* d_in, const int* in_sizes, int n_in,
                              void* d_out, int out_size, void* d_ws, size_t ws_size,
                              hipStream_t stream) {
    const float* x    = (const float*)d_in[0];
    const float* W    = (const float*)d_in[1];
    const float* U    = (const float*)d_in[2];
    const float* bv   = (const float*)d_in[3];
    const float* Wd   = (const float*)d_in[4];
    const float* bd   = (const float*)d_in[5];
    float* out = (float*)d_out;

    dim3 grid(BATCH / NB);    // 256 independent waves, 1 per CU
    dim3 block(64);           // single wave, no barriers, no LDS
    gru_1w<<<grid, block, 0, stream>>>(x, W, U, bv, Wd, bd, out);
}

// Round 4
// 297.122 us; speedup vs baseline: 1.0532x; 1.0532x over previous
//
#include <hip/hip_runtime.h>
#include <math.h>

typedef _Float16 v8h __attribute__((ext_vector_type(8)));
typedef float v4f __attribute__((ext_vector_type(4)));

#define UNITS    50
#define K3       150
#define FDIM     64
#define TSTEPS   128
#define BATCH    4096
#define NB       16     // batch rows per block tile (MFMA M)
#define H16S     72     // halves per h row (50 h + slot50=1.0 + pad); 144 B stride, 16B-aligned
#define H32S     52

#if __has_builtin(__builtin_amdgcn_exp2f)
__device__ __forceinline__ float fast_exp2(float x) { return __builtin_amdgcn_exp2f(x); }
#else
__device__ __forceinline__ float fast_exp2(float x) { return exp2f(x); }
#endif
#if __has_builtin(__builtin_amdgcn_rcpf)
__device__ __forceinline__ float fast_rcp(float x) { return __builtin_amdgcn_rcpf(x); }
#else
__device__ __forceinline__ float fast_rcp(float x) { return 1.0f / x; }
#endif

__device__ __forceinline__ int imin2(int a, int b) { return a < b ? a : b; }

// 4 waves per block, one 16-batch tile per block. Wave nt owns u-columns
// nt*16..nt*16+15 and computes ALL THREE gates for them. Waves couple only
// through the f16 h exchange (ping-pong LDS buffers).
//
// Round-4 change: s_barrier per step REPLACED by a monotone LDS flag
// handshake. Rationale: wall time = 128 x single-chain step latency; rounds
// 1-3 exonerated the waitcnt drain, the x-work placement, and LDS/barrier
// *existence* (the barrier-free 1-wave design was slower because it piles all
// work on one SIMD). The remaining untested stall component of the 2475-cy
// step is the full-workgroup sleep/wake of s_barrier with ONE block per CU
// (nothing hides the wake). Flag protocol:
//   producer (end of step t): ds_write h(t+1) slice -> s_waitcnt lgkmcnt(0)
//                             -> lane0 posts flags[wave] = t+1
//   consumer (top of step t): spin until min(flags[0..3]) >= t
// Race-freedom with 2 buffers: a wave writing buf[(t+1)&1] at step t has
// observed all flags >= t, so every wave finished reading that buffer at its
// step t-1. Max skew = 1 step. Counters are monotone -> no wraparound, no
// livelock. Math untouched -> absmax must be bit-identical (0.00390625).
__global__ __launch_bounds__(256, 1)
void gru_4w(const float* __restrict__ x, const float* __restrict__ W,
            const float* __restrict__ U, const float* __restrict__ bv,
            const float* __restrict__ Wd, const float* __restrict__ bd,
            float* __restrict__ out) {
    __shared__ _Float16 hs16[2][NB * H16S];   // ping-pong h state (f16)
    __shared__ float    hs32[NB * H32S];      // epilogue only
    __shared__ int      flags[4] __attribute__((aligned(16)));

    const int tid  = threadIdx.x;
    const int nt   = tid >> 6;          // wave id = ntile (wave-uniform)
    const int lane = tid & 63;
    const int n    = lane & 15;
    const int quad = lane >> 4;
    const int b0   = blockIdx.x * NB;
    const int c    = nt * 16 + n;       // this lane's unit column (>=50 for tail of wave 3)

    // ---- init h buffers (zeros + 1.0 at slot u=50) and flags ----
    for (int i = tid; i < NB * H16S; i += 256) {
        _Float16 v = ((i % H16S) == 50) ? (_Float16)1.f : (_Float16)0.f;
        hs16[0][i] = v;
        hs16[1][i] = v;
    }
    if (tid < 4) flags[tid] = 0;

    // ---- B fragments for this wave's ntile (VGPR-resident whole kernel) ----
    // combined K rows: 0..63 = W, 64..113 = U, 114 = b[1] h-col fold, rest 0
    v8h Bz[4], Br[4], Bh[4];
    #pragma unroll
    for (int kt = 0; kt < 4; ++kt) {
        v8h fz, fr, fh;
        #pragma unroll
        for (int j = 0; j < 8; ++j) {
            const int k = kt * 32 + quad * 8 + j;
            float vz = 0.f, vr = 0.f, vh = 0.f;
            if (c < UNITS) {
                if (k < FDIM) {
                    vz = W[k * K3 + c];
                    vr = W[k * K3 + 50 + c];
                    vh = W[k * K3 + 100 + c];
                } else if (k < FDIM + UNITS) {
                    const int ur = k - FDIM;
                    vz = U[ur * K3 + c];
                    vr = U[ur * K3 + 50 + c];
                    vh = U[ur * K3 + 100 + c];
                } else if (k == FDIM + UNITS) {
                    vh = bv[250 + c];           // b[1] h-col via h-slot u=50 == 1.0
                }
            }
            fz[j] = (_Float16)vz; fr[j] = (_Float16)vr; fh[j] = (_Float16)vh;
        }
        Bz[kt] = fz; Br[kt] = fr; Bh[kt] = fh;
    }

    // ---- sigmoid-folded bias constants for this lane's column ----
    const float CE = -1.44269504f;      // sigmoid(a) = 1 / (1 + 2^(CE*a))
    float bzc = 0.f, brc = 0.f, bx = 0.f;
    if (c < UNITS) {
        bzc = CE * (bv[c]      + bv[150 + c]);
        brc = CE * (bv[50 + c] + bv[200 + c]);
        bx  = bv[100 + c];
    }

    // f32 h state in registers: h32[r] = h[m=quad*4+r][u=c]
    v4f h32 = {0.f, 0.f, 0.f, 0.f};

    const float* xbase = x + ((size_t)(b0 + n) * TSTEPS) * FDIM + quad * 8;

    // x-partial MFMAs for one step (accumulate order unchanged -> bit-identical)
    v4f az_x, ar_x, ax_x;
    auto xpart = [&](const v4f& q0, const v4f& q1, const v4f& q2, const v4f& q3) {
        v8h A0, A1;
        #pragma unroll
        for (int j = 0; j < 4; ++j) {
            A0[j]     = (_Float16)q0[j];
            A0[j + 4] = (_Float16)q1[j];
            A1[j]     = (_Float16)q2[j];
            A1[j + 4] = (_Float16)q3[j];
        }
        const v4f zero4 = {0.f, 0.f, 0.f, 0.f};
        az_x = __builtin_amdgcn_mfma_f32_16x16x32_f16(A0, Bz[0], zero4, 0, 0, 0);
        az_x = __builtin_amdgcn_mfma_f32_16x16x32_f16(A1, Bz[1], az_x,  0, 0, 0);
        ar_x = __builtin_amdgcn_mfma_f32_16x16x32_f16(A0, Br[0], zero4, 0, 0, 0);
        ar_x = __builtin_amdgcn_mfma_f32_16x16x32_f16(A1, Br[1], ar_x,  0, 0, 0);
        v4f axi = {bx, bx, bx, bx};
        ax_x = __builtin_amdgcn_mfma_f32_16x16x32_f16(A0, Bh[0], axi,  0, 0, 0);
        ax_x = __builtin_amdgcn_mfma_f32_16x16x32_f16(A1, Bh[1], ax_x, 0, 0, 0);
    };

    // ---- prologue: x(0) partials now; prefetch x(1) and x(2) into regs ----
    {
        v4f q0 = *(const v4f*)(xbase + 0);
        v4f q1 = *(const v4f*)(xbase + 4);
        v4f q2 = *(const v4f*)(xbase + 32);
        v4f q3 = *(const v4f*)(xbase + 36);
        xpart(q0, q1, q2, q3);
    }
    v4f pxO[4], pxE[4];   // pxO = x(t+1) for even t, pxE = x(t+1) for odd t
    {
        const float* x1 = xbase + (size_t)1 * FDIM;
        pxO[0] = *(const v4f*)(x1 + 0);  pxO[1] = *(const v4f*)(x1 + 4);
        pxO[2] = *(const v4f*)(x1 + 32); pxO[3] = *(const v4f*)(x1 + 36);
        const float* x2 = xbase + (size_t)2 * FDIM;
        pxE[0] = *(const v4f*)(x2 + 0);  pxE[1] = *(const v4f*)(x2 + 4);
        pxE[2] = *(const v4f*)(x2 + 32); pxE[3] = *(const v4f*)(x2 + 36);
    }

    __syncthreads();   // one-time: hs16 init + flags visible

    volatile int* vflags = (volatile int*)flags;

    auto step = [&](int t, v4f (&px)[4]) {
        // ---- consumer sync: h(t) fully published? (flags monotone) ----
        // t=0 passes immediately (flags start at 0).
        while (true) {
            const int f0 = vflags[0];
            const int f1 = vflags[1];
            const int f2 = vflags[2];
            const int f3 = vflags[3];
            if (imin2(imin2(f0, f1), imin2(f2, f3)) >= t) break;
        }
        asm volatile("" ::: "memory");          // no ds_read hoists above the spin
        __builtin_amdgcn_sched_barrier(0);

        const _Float16* hrd = hs16[t & 1];
        _Float16*       hwr = hs16[(t + 1) & 1];

        // post-sync critical path: h fragment read + 2-deep MFMA chains
        v8h A2 = *(const v8h*)(&hrd[n * H16S + quad * 8]);       // k 64..95  (h 0..31)
        v8h A3 = *(const v8h*)(&hrd[n * H16S + 32 + quad * 8]);  // k 96..127 (h 32..49, 1.0, 0s)

        const v4f zero4 = {0.f, 0.f, 0.f, 0.f};
        v4f az = __builtin_amdgcn_mfma_f32_16x16x32_f16(A2, Bz[2], az_x, 0, 0, 0);
        az     = __builtin_amdgcn_mfma_f32_16x16x32_f16(A3, Bz[3], az,   0, 0, 0);
        v4f ar = __builtin_amdgcn_mfma_f32_16x16x32_f16(A2, Br[2], ar_x, 0, 0, 0);
        ar     = __builtin_amdgcn_mfma_f32_16x16x32_f16(A3, Br[3], ar,   0, 0, 0);
        v4f ah = __builtin_amdgcn_mfma_f32_16x16x32_f16(A2, Bh[2], zero4, 0, 0, 0);
        ah     = __builtin_amdgcn_mfma_f32_16x16x32_f16(A3, Bh[3], ah,    0, 0, 0);
        v4f ax = ax_x;

        // shadow work for step t+1: f32->f16 convert + 6 x-MFMAs + prefetch x(t+3)
        if (t + 1 < TSTEPS) {
            xpart(px[0], px[1], px[2], px[3]);
            if (t + 3 < TSTEPS) {
                const float* xp = xbase + (size_t)(t + 3) * FDIM;
                px[0] = *(const v4f*)(xp + 0);
                px[1] = *(const v4f*)(xp + 4);
                px[2] = *(const v4f*)(xp + 32);
                px[3] = *(const v4f*)(xp + 36);
            }
        }

        // register-local gate math: 4 rows (m = quad*4 + r)
        #pragma unroll
        for (int r = 0; r < 4; ++r) {
            const float ez = fast_exp2(fmaf(az[r], CE, bzc));
            const float er = fast_exp2(fmaf(ar[r], CE, brc));
            const float pz = 1.f + ez;
            const float pr = 1.f + er;
            const float d  = fast_rcp(pz * pr);
            const float zg = d * pr;                 // sigmoid(z-pre)
            const float rg = d * pz;                 // sigmoid(r-pre)
            const float hc = fmaxf(fmaf(rg, ah[r], ax[r]), 0.f);  // ah includes b[1]
            const float hn = fmaf(zg, h32[r] - hc, hc);           // z*h + (1-z)*hc
            h32[r] = hn;
            if (c < UNITS)
                hwr[(quad * 4 + r) * H16S + c] = (_Float16)hn;
        }

        // ---- producer sync: drain the h writes, then post flag = t+1 ----
        asm volatile("s_waitcnt lgkmcnt(0)" ::: "memory");
        if (lane == 0) vflags[nt] = t + 1;
        __builtin_amdgcn_sched_barrier(0);
    };

    #pragma unroll 1
    for (int t = 0; t < TSTEPS; t += 2) {
        step(t,     pxO);
        step(t + 1, pxE);
    }

    // ---- epilogue: out[b] = h_T @ Wd + bd (exact f32 h) ----
    // (hs32 is a separate buffer; the one __syncthreads here is off the loop.)
    if (c < UNITS) {
        #pragma unroll
        for (int r = 0; r < 4; ++r)
            hs32[(quad * 4 + r) * H32S + c] = h32[r];
    }
    __syncthreads();
    if (tid < NB) {
        float acc = bd[0];
        #pragma unroll
        for (int u = 0; u < UNITS; ++u)
            acc = fmaf(hs32[tid * H32S + u], Wd[u], acc);
        out[b0 + tid] = acc;
    }
}

extern "C" void kernel_launch(void* const* d_in, const int* in_sizes, int n_in,
                              void* d_out, int out_size, void* d_ws, size_t ws_size,
                              hipStream_t stream) {
    const float* x    = (const float*)d_in[0];
    const float* W    = (const float*)d_in[1];
    const float* U    = (const float*)d_in[2];
    const float* bv   = (const float*)d_in[3];
    const float* Wd   = (const float*)d_in[4];
    const float* bd   = (const float*)d_in[5];
    float* out = (float*)d_out;

    dim3 grid(BATCH / NB);    // 256 blocks -> 1 per CU
    dim3 block(256);          // 4 waves, one per SIMD
    gru_4w<<<grid, block, 0, stream>>>(x, W, U, bv, Wd, bd, out);
}

// Round 5
// 294.094 us; speedup vs baseline: 1.0641x; 1.0103x over previous
//
#include <hip/hip_runtime.h>
#include <math.h>

typedef _Float16 v8h __attribute__((ext_vector_type(8)));
typedef float v4f __attribute__((ext_vector_type(4)));

#define UNITS    50
#define K3       150
#define FDIM     64
#define TSTEPS   128
#define BATCH    4096
#define NB       16     // batch rows per block tile (MFMA M)
#define NCHAIN   (BATCH / NB)   // 256 recurrence blocks (1 per CU)
#define H16S     72     // halves per h row (50 h + slot50=1.0 + pad); 144 B stride, 16B-aligned
#define H32S     52

#if __has_builtin(__builtin_amdgcn_exp2f)
__device__ __forceinline__ float fast_exp2(float x) { return __builtin_amdgcn_exp2f(x); }
#else
__device__ __forceinline__ float fast_exp2(float x) { return exp2f(x); }
#endif
#if __has_builtin(__builtin_amdgcn_rcpf)
__device__ __forceinline__ float fast_rcp(float x) { return __builtin_amdgcn_rcpf(x); }
#else
__device__ __forceinline__ float fast_rcp(float x) { return 1.0f / x; }
#endif

// Theory (round 5): all prior designs sit at their structural floor at an
// EFFECTIVE CLOCK of ~0.9 GHz — the DPM governor never ramps for this
// latency-bound, 18%-VALU kernel. Evidence: per-step cycle counts of three
// very different structures (930 / 1026 / 1211 "real" cycles) match their
// bottom-up critical-path estimates ONLY at ~0.9 GHz, and measured VALUBusy
// (17-18%) matches the bottom-up busy-cycle count at 0.9 GHz (19%), not at
// 2.4 GHz (7%).
//
// Fix attempt: co-schedule 256 HEATER blocks (blocks 256..511, one more per
// CU) that saturate VALU issue with register FMAs at wave priority 0. The
// chain blocks (0..255) are the UNCHANGED proven 132-us kernel at priority 1.
// Clock DPM is chip-level, so heaters ramp the clock for all CUs. Heaters
// exit when a device-scope counter (d_ws, zeroed via hipMemsetAsync each
// launch) reaches NCHAIN, with a hard iteration cap as a safety net.
__global__ __launch_bounds__(256, 2)
void gru_4w(const float* __restrict__ x, const float* __restrict__ W,
            const float* __restrict__ U, const float* __restrict__ bv,
            const float* __restrict__ Wd, const float* __restrict__ bd,
            float* __restrict__ out, unsigned* __restrict__ done) {
    __shared__ _Float16 hs16[2][NB * H16S];   // ping-pong h state (f16)
    __shared__ float    hs32[NB * H32S];      // epilogue only

    // ================= HEATER BLOCKS =================
    if (blockIdx.x >= NCHAIN) {
        // dense independent FMA stream: ~full VALU issue on this SIMD slot
        float a0 = 1.0f + (float)threadIdx.x * 1e-6f;
        float a1 = 0.25f, a2 = 0.5f, a3 = 0.75f;
        float a4 = 1.25f, a5 = 1.5f, a6 = 1.75f, a7 = 2.0f;
        const float m = 0.9999999f, c = 1e-7f;
        for (int outer = 0; outer < 4096; ++outer) {          // hard cap ~4 ms
            #pragma unroll
            for (int i = 0; i < 128; ++i) {                   // 1024 FMAs / poll
                a0 = fmaf(a0, m, c); a1 = fmaf(a1, m, c);
                a2 = fmaf(a2, m, c); a3 = fmaf(a3, m, c);
                a4 = fmaf(a4, m, c); a5 = fmaf(a5, m, c);
                a6 = fmaf(a6, m, c); a7 = fmaf(a7, m, c);
            }
            if (__hip_atomic_load(done, __ATOMIC_RELAXED,
                                  __HIP_MEMORY_SCOPE_AGENT) >= NCHAIN)
                break;
        }
        // keep the FMA stream live without any memory side effect (rule 17)
        asm volatile("" :: "v"(a0), "v"(a1), "v"(a2), "v"(a3),
                           "v"(a4), "v"(a5), "v"(a6), "v"(a7));
        return;
    }

    // ================= CHAIN BLOCKS (unchanged 132-us kernel) =================
    __builtin_amdgcn_s_setprio(1);      // win issue arbitration vs heater wave

    const int tid  = threadIdx.x;
    const int nt   = tid >> 6;          // wave id = ntile (wave-uniform)
    const int lane = tid & 63;
    const int n    = lane & 15;
    const int quad = lane >> 4;
    const int b0   = blockIdx.x * NB;
    const int c    = nt * 16 + n;       // this lane's unit column (>=50 for tail of wave 3)

    // ---- init both h buffers: zeros, constant 1.0 at slot u=50 (bias-fold row) ----
    for (int i = tid; i < NB * H16S; i += 256) {
        _Float16 v = ((i % H16S) == 50) ? (_Float16)1.f : (_Float16)0.f;
        hs16[0][i] = v;
        hs16[1][i] = v;
    }

    // ---- B fragments for this wave's ntile (VGPR-resident whole kernel) ----
    // combined K rows: 0..63 = W, 64..113 = U, 114 = b[1] h-col fold, rest 0
    v8h Bz[4], Br[4], Bh[4];
    #pragma unroll
    for (int kt = 0; kt < 4; ++kt) {
        v8h fz, fr, fh;
        #pragma unroll
        for (int j = 0; j < 8; ++j) {
            const int k = kt * 32 + quad * 8 + j;
            float vz = 0.f, vr = 0.f, vh = 0.f;
            if (c < UNITS) {
                if (k < FDIM) {
                    vz = W[k * K3 + c];
                    vr = W[k * K3 + 50 + c];
                    vh = W[k * K3 + 100 + c];
                } else if (k < FDIM + UNITS) {
                    const int ur = k - FDIM;
                    vz = U[ur * K3 + c];
                    vr = U[ur * K3 + 50 + c];
                    vh = U[ur * K3 + 100 + c];
                } else if (k == FDIM + UNITS) {
                    vh = bv[250 + c];           // b[1] h-col via h-slot u=50 == 1.0
                }
            }
            fz[j] = (_Float16)vz; fr[j] = (_Float16)vr; fh[j] = (_Float16)vh;
        }
        Bz[kt] = fz; Br[kt] = fr; Bh[kt] = fh;
    }

    // ---- sigmoid-folded bias constants for this lane's column ----
    const float CE = -1.44269504f;      // sigmoid(a) = 1 / (1 + 2^(CE*a))
    float bzc = 0.f, brc = 0.f, bx = 0.f;
    if (c < UNITS) {
        bzc = CE * (bv[c]      + bv[150 + c]);
        brc = CE * (bv[50 + c] + bv[200 + c]);
        bx  = bv[100 + c];
    }

    // f32 h state in registers: h32[r] = h[m=quad*4+r][u=c]
    v4f h32 = {0.f, 0.f, 0.f, 0.f};

    // ---- x prefetch for t=0 (lane covers batch row b0+n, k=quad*8..+7, +32) ----
    const float* xbase = x + ((size_t)(b0 + n) * TSTEPS) * FDIM + quad * 8;
    v4f px0 = *(const v4f*)(xbase + 0);
    v4f px1 = *(const v4f*)(xbase + 4);
    v4f px2 = *(const v4f*)(xbase + 32);
    v4f px3 = *(const v4f*)(xbase + 36);

    __syncthreads();

    for (int t = 0; t < TSTEPS; ++t) {
        const _Float16* hrd = hs16[t & 1];
        _Float16*       hwr = hs16[(t + 1) & 1];

        // A fragments: x part from regs, h part from LDS
        v8h A0, A1;
        #pragma unroll
        for (int j = 0; j < 4; ++j) {
            A0[j]     = (_Float16)px0[j];
            A0[j + 4] = (_Float16)px1[j];
            A1[j]     = (_Float16)px2[j];
            A1[j + 4] = (_Float16)px3[j];
        }
        v8h A2 = *(const v8h*)(&hrd[n * H16S + quad * 8]);       // k 64..95  (h 0..31)
        v8h A3 = *(const v8h*)(&hrd[n * H16S + 32 + quad * 8]);  // k 96..127 (h 32..49, 1.0, 0s)

        if (t + 1 < TSTEPS) {
            const float* xp = xbase + (size_t)(t + 1) * FDIM;
            px0 = *(const v4f*)(xp + 0);
            px1 = *(const v4f*)(xp + 4);
            px2 = *(const v4f*)(xp + 32);
            px3 = *(const v4f*)(xp + 36);
        }

        const v4f zero4 = {0.f, 0.f, 0.f, 0.f};
        // x-dependent MFMAs first (ready from regs), h-dependent after
        v4f ax = {bx, bx, bx, bx};
        v4f az = __builtin_amdgcn_mfma_f32_16x16x32_f16(A0, Bz[0], zero4, 0, 0, 0);
        az     = __builtin_amdgcn_mfma_f32_16x16x32_f16(A1, Bz[1], az,    0, 0, 0);
        v4f ar = __builtin_amdgcn_mfma_f32_16x16x32_f16(A0, Br[0], zero4, 0, 0, 0);
        ar     = __builtin_amdgcn_mfma_f32_16x16x32_f16(A1, Br[1], ar,    0, 0, 0);
        ax     = __builtin_amdgcn_mfma_f32_16x16x32_f16(A0, Bh[0], ax,    0, 0, 0);
        ax     = __builtin_amdgcn_mfma_f32_16x16x32_f16(A1, Bh[1], ax,    0, 0, 0);
        az     = __builtin_amdgcn_mfma_f32_16x16x32_f16(A2, Bz[2], az,    0, 0, 0);
        az     = __builtin_amdgcn_mfma_f32_16x16x32_f16(A3, Bz[3], az,    0, 0, 0);
        ar     = __builtin_amdgcn_mfma_f32_16x16x32_f16(A2, Br[2], ar,    0, 0, 0);
        ar     = __builtin_amdgcn_mfma_f32_16x16x32_f16(A3, Br[3], ar,    0, 0, 0);
        v4f ah = __builtin_amdgcn_mfma_f32_16x16x32_f16(A2, Bh[2], zero4, 0, 0, 0);
        ah     = __builtin_amdgcn_mfma_f32_16x16x32_f16(A3, Bh[3], ah,    0, 0, 0);

        // register-local gate math: 4 rows (m = quad*4 + r)
        #pragma unroll
        for (int r = 0; r < 4; ++r) {
            const float ez = fast_exp2(fmaf(az[r], CE, bzc));
            const float er = fast_exp2(fmaf(ar[r], CE, brc));
            const float pz = 1.f + ez;
            const float pr = 1.f + er;
            const float d  = fast_rcp(pz * pr);
            const float zg = d * pr;                 // sigmoid(z-pre)
            const float rg = d * pz;                 // sigmoid(r-pre)
            const float hc = fmaxf(fmaf(rg, ah[r], ax[r]), 0.f);  // ah includes b[1]
            const float hn = fmaf(zg, h32[r] - hc, hc);           // z*h + (1-z)*hc
            h32[r] = hn;
            if (c < UNITS)
                hwr[(quad * 4 + r) * H16S + c] = (_Float16)hn;
        }
        __syncthreads();   // orders h writes (t+1 buf) vs next step's reads
    }

    // ---- epilogue: out[b] = h_T @ Wd + bd (exact f32 h) ----
    if (c < UNITS) {
        #pragma unroll
        for (int r = 0; r < 4; ++r)
            hs32[(quad * 4 + r) * H32S + c] = h32[r];
    }
    __syncthreads();
    if (tid < NB) {
        float acc = bd[0];
        #pragma unroll
        for (int u = 0; u < UNITS; ++u)
            acc = fmaf(hs32[tid * H32S + u], Wd[u], acc);
        out[b0 + tid] = acc;
    }

    // signal heaters (counter-only semantics; no ordering needed)
    if (done && tid == 0) atomicAdd(done, 1u);
}

extern "C" void kernel_launch(void* const* d_in, const int* in_sizes, int n_in,
                              void* d_out, int out_size, void* d_ws, size_t ws_size,
                              hipStream_t stream) {
    const float* x    = (const float*)d_in[0];
    const float* W    = (const float*)d_in[1];
    const float* U    = (const float*)d_in[2];
    const float* bv   = (const float*)d_in[3];
    const float* Wd   = (const float*)d_in[4];
    const float* bd   = (const float*)d_in[5];
    float* out = (float*)d_out;

    if (ws_size >= sizeof(unsigned)) {
        unsigned* done = (unsigned*)d_ws;
        hipMemsetAsync(done, 0, sizeof(unsigned), stream);
        dim3 grid(2 * NCHAIN);    // 256 chain blocks + 256 heater blocks (2/CU)
        dim3 block(256);
        gru_4w<<<grid, block, 0, stream>>>(x, W, U, bv, Wd, bd, out, done);
    } else {
        dim3 grid(NCHAIN);        // fallback: no workspace -> no heaters
        dim3 block(256);
        gru_4w<<<grid, block, 0, stream>>>(x, W, U, bv, Wd, bd, out, nullptr);
    }
}

// Round 6
// 273.267 us; speedup vs baseline: 1.1452x; 1.0762x over previous
//
#include <hip/hip_runtime.h>
#include <math.h>

typedef _Float16 v8h __attribute__((ext_vector_type(8)));
typedef float v4f __attribute__((ext_vector_type(4)));

#define UNITS    50
#define K3       150
#define FDIM     64
#define TSTEPS   128
#define BATCH    4096
#define NB       16     // batch rows per block tile (MFMA M)
#define H16S     72     // halves per h row (50 h + slot50=1.0 + pad); 144 B stride, 16B-aligned
#define H32S     52

#if __has_builtin(__builtin_amdgcn_exp2f)
__device__ __forceinline__ float fast_exp2(float x) { return __builtin_amdgcn_exp2f(x); }
#else
__device__ __forceinline__ float fast_exp2(float x) { return exp2f(x); }
#endif
#if __has_builtin(__builtin_amdgcn_rcpf)
__device__ __forceinline__ float fast_rcp(float x) { return __builtin_amdgcn_rcpf(x); }
#else
__device__ __forceinline__ float fast_rcp(float x) { return 1.0f / x; }
#endif

// FINAL (reverted to the round-0 best after 5 falsification rounds).
//
// 4 waves per block, one 16-batch tile per block. Wave nt owns u-columns
// nt*16..nt*16+15 and computes ALL THREE gates for them -> Z/R/HX/HH stay
// lane- and register-aligned, gate math is register-local. Waves couple only
// through the f16 h exchange (ping-pong LDS buffers, one barrier per step).
//
// Why no further: the per-step cost (~1.0 us) is a LATENCY floor, not a pipe
// floor. Evidence (dispatch us): barrier drain removal + full shadow
// pipelining = 133 (r1, no change); 2 blocks/CU = 146 (r2: half work per
// block, LONGER step -> step cost is work-insensitive); barrier-free
// register-local single-wave redesign = 172 (r3: single-SIMD issue
// concentration); LDS flag handshake instead of s_barrier = 154 (r4);
// VALU-saturating heater blocks = 152 with VALUBusy 70% (r5: clock/DPM
// exonerated). Chain per step: h-exchange (ds_write -> lgkm drain -> sync ->
// ds_read) + dependent MFMA pair + MFMA->VALU forwarding + 9-deep trans/VALU
// gate chain. 128 serial steps x ~1.0 us = ~131 us/dispatch. Escape routes
// priced out: precomputing x@W as a parallel GEMM adds a 315-630 MB HBM
// round-trip (63-126 us) for ~30 us of step savings; batch = 256 CU x 16
// rows exactly, so no spare parallelism exists to hide the recurrence.
__global__ __launch_bounds__(256, 1)
void gru_4w(const float* __restrict__ x, const float* __restrict__ W,
            const float* __restrict__ U, const float* __restrict__ bv,
            const float* __restrict__ Wd, const float* __restrict__ bd,
            float* __restrict__ out) {
    __shared__ _Float16 hs16[2][NB * H16S];   // ping-pong h state (f16)
    __shared__ float    hs32[NB * H32S];      // epilogue only

    const int tid  = threadIdx.x;
    const int nt   = tid >> 6;          // wave id = ntile (wave-uniform)
    const int lane = tid & 63;
    const int n    = lane & 15;
    const int quad = lane >> 4;
    const int b0   = blockIdx.x * NB;
    const int c    = nt * 16 + n;       // this lane's unit column (>=50 for tail of wave 3)

    // ---- init both h buffers: zeros, constant 1.0 at slot u=50 (bias-fold row) ----
    for (int i = tid; i < NB * H16S; i += 256) {
        _Float16 v = ((i % H16S) == 50) ? (_Float16)1.f : (_Float16)0.f;
        hs16[0][i] = v;
        hs16[1][i] = v;
    }

    // ---- B fragments for this wave's ntile (VGPR-resident whole kernel) ----
    // combined K rows: 0..63 = W, 64..113 = U, 114 = b[1] h-col fold, rest 0
    v8h Bz[4], Br[4], Bh[4];
    #pragma unroll
    for (int kt = 0; kt < 4; ++kt) {
        v8h fz, fr, fh;
        #pragma unroll
        for (int j = 0; j < 8; ++j) {
            const int k = kt * 32 + quad * 8 + j;
            float vz = 0.f, vr = 0.f, vh = 0.f;
            if (c < UNITS) {
                if (k < FDIM) {
                    vz = W[k * K3 + c];
                    vr = W[k * K3 + 50 + c];
                    vh = W[k * K3 + 100 + c];
                } else if (k < FDIM + UNITS) {
                    const int ur = k - FDIM;
                    vz = U[ur * K3 + c];
                    vr = U[ur * K3 + 50 + c];
                    vh = U[ur * K3 + 100 + c];
                } else if (k == FDIM + UNITS) {
                    vh = bv[250 + c];           // b[1] h-col via h-slot u=50 == 1.0
                }
            }
            fz[j] = (_Float16)vz; fr[j] = (_Float16)vr; fh[j] = (_Float16)vh;
        }
        Bz[kt] = fz; Br[kt] = fr; Bh[kt] = fh;
    }

    // ---- sigmoid-folded bias constants for this lane's column ----
    const float CE = -1.44269504f;      // sigmoid(a) = 1 / (1 + 2^(CE*a))
    float bzc = 0.f, brc = 0.f, bx = 0.f;
    if (c < UNITS) {
        bzc = CE * (bv[c]      + bv[150 + c]);
        brc = CE * (bv[50 + c] + bv[200 + c]);
        bx  = bv[100 + c];
    }

    // f32 h state in registers: h32[r] = h[m=quad*4+r][u=c]
    v4f h32 = {0.f, 0.f, 0.f, 0.f};

    // ---- x prefetch for t=0 (lane covers batch row b0+n, k=quad*8..+7, +32) ----
    const float* xbase = x + ((size_t)(b0 + n) * TSTEPS) * FDIM + quad * 8;
    v4f px0 = *(const v4f*)(xbase + 0);
    v4f px1 = *(const v4f*)(xbase + 4);
    v4f px2 = *(const v4f*)(xbase + 32);
    v4f px3 = *(const v4f*)(xbase + 36);

    __syncthreads();

    for (int t = 0; t < TSTEPS; ++t) {
        const _Float16* hrd = hs16[t & 1];
        _Float16*       hwr = hs16[(t + 1) & 1];

        // A fragments: x part from regs, h part from LDS
        v8h A0, A1;
        #pragma unroll
        for (int j = 0; j < 4; ++j) {
            A0[j]     = (_Float16)px0[j];
            A0[j + 4] = (_Float16)px1[j];
            A1[j]     = (_Float16)px2[j];
            A1[j + 4] = (_Float16)px3[j];
        }
        v8h A2 = *(const v8h*)(&hrd[n * H16S + quad * 8]);       // k 64..95  (h 0..31)
        v8h A3 = *(const v8h*)(&hrd[n * H16S + 32 + quad * 8]);  // k 96..127 (h 32..49, 1.0, 0s)

        if (t + 1 < TSTEPS) {
            const float* xp = xbase + (size_t)(t + 1) * FDIM;
            px0 = *(const v4f*)(xp + 0);
            px1 = *(const v4f*)(xp + 4);
            px2 = *(const v4f*)(xp + 32);
            px3 = *(const v4f*)(xp + 36);
        }

        const v4f zero4 = {0.f, 0.f, 0.f, 0.f};
        // x-dependent MFMAs first (ready from regs), h-dependent after
        v4f ax = {bx, bx, bx, bx};
        v4f az = __builtin_amdgcn_mfma_f32_16x16x32_f16(A0, Bz[0], zero4, 0, 0, 0);
        az     = __builtin_amdgcn_mfma_f32_16x16x32_f16(A1, Bz[1], az,    0, 0, 0);
        v4f ar = __builtin_amdgcn_mfma_f32_16x16x32_f16(A0, Br[0], zero4, 0, 0, 0);
        ar     = __builtin_amdgcn_mfma_f32_16x16x32_f16(A1, Br[1], ar,    0, 0, 0);
        ax     = __builtin_amdgcn_mfma_f32_16x16x32_f16(A0, Bh[0], ax,    0, 0, 0);
        ax     = __builtin_amdgcn_mfma_f32_16x16x32_f16(A1, Bh[1], ax,    0, 0, 0);
        az     = __builtin_amdgcn_mfma_f32_16x16x32_f16(A2, Bz[2], az,    0, 0, 0);
        az     = __builtin_amdgcn_mfma_f32_16x16x32_f16(A3, Bz[3], az,    0, 0, 0);
        ar     = __builtin_amdgcn_mfma_f32_16x16x32_f16(A2, Br[2], ar,    0, 0, 0);
        ar     = __builtin_amdgcn_mfma_f32_16x16x32_f16(A3, Br[3], ar,    0, 0, 0);
        v4f ah = __builtin_amdgcn_mfma_f32_16x16x32_f16(A2, Bh[2], zero4, 0, 0, 0);
        ah     = __builtin_amdgcn_mfma_f32_16x16x32_f16(A3, Bh[3], ah,    0, 0, 0);

        // register-local gate math: 4 rows (m = quad*4 + r)
        #pragma unroll
        for (int r = 0; r < 4; ++r) {
            const float ez = fast_exp2(fmaf(az[r], CE, bzc));
            const float er = fast_exp2(fmaf(ar[r], CE, brc));
            const float pz = 1.f + ez;
            const float pr = 1.f + er;
            const float d  = fast_rcp(pz * pr);
            const float zg = d * pr;                 // sigmoid(z-pre)
            const float rg = d * pz;                 // sigmoid(r-pre)
            const float hc = fmaxf(fmaf(rg, ah[r], ax[r]), 0.f);  // ah includes b[1]
            const float hn = fmaf(zg, h32[r] - hc, hc);           // z*h + (1-z)*hc
            h32[r] = hn;
            if (c < UNITS)
                hwr[(quad * 4 + r) * H16S + c] = (_Float16)hn;
        }
        __syncthreads();   // orders h writes (t+1 buf) vs next step's reads
    }

    // ---- epilogue: out[b] = h_T @ Wd + bd (exact f32 h) ----
    if (c < UNITS) {
        #pragma unroll
        for (int r = 0; r < 4; ++r)
            hs32[(quad * 4 + r) * H32S + c] = h32[r];
    }
    __syncthreads();
    if (tid < NB) {
        float acc = bd[0];
        #pragma unroll
        for (int u = 0; u < UNITS; ++u)
            acc = fmaf(hs32[tid * H32S + u], Wd[u], acc);
        out[b0 + tid] = acc;
    }
}

extern "C" void kernel_launch(void* const* d_in, const int* in_sizes, int n_in,
                              void* d_out, int out_size, void* d_ws, size_t ws_size,
                              hipStream_t stream) {
    const float* x    = (const float*)d_in[0];
    const float* W    = (const float*)d_in[1];
    const float* U    = (const float*)d_in[2];
    const float* bv   = (const float*)d_in[3];
    const float* Wd   = (const float*)d_in[4];
    const float* bd   = (const float*)d_in[5];
    float* out = (float*)d_out;

    dim3 grid(BATCH / NB);    // 256 blocks -> 1 per CU
    dim3 block(256);          // 4 waves, one per SIMD
    gru_4w<<<grid, block, 0, stream>>>(x, W, U, bv, Wd, bd, out);
}